// Round 1
// baseline (165.199 us; speedup 1.0000x reference)
//
#include <hip/hip_runtime.h>
#include <hip/hip_bf16.h>

// Problem constants (fixed by setup_inputs)
#define BB   4
#define CF   256
#define CC   64
#define CP   80
#define HH   128   // hi-res
#define WW   128
#define HL   64    // lo-res
#define WL   64
#define KK   25
#define NPIX 16384 // 128*128

// ---------------- Kernel A: compress (1x1 conv, GEMM) -------------------
// guide[b][o][p] = sum_c feat[b][c][p] * wc[o][c] + bc[o]
// grid: 256 blocks (4 b x 64 pixel tiles of 256), block 256 threads.
// Per thread: 8 outputs x 8 pixels register tile.
__global__ __launch_bounds__(256) void k_compress(
    const float* __restrict__ feat, const float* __restrict__ wc,
    const float* __restrict__ bc, float* __restrict__ guide) {
  __shared__ float Wl[CF * 65];   // [c][o] transposed, pad 65 -> conflict-free
  __shared__ float Fl[16 * 256];  // [cc][p]
  const int tid = threadIdx.x;
  const int bx = blockIdx.x;
  const int b = bx >> 6;
  const int p0 = (bx & 63) << 8;

  // Load W transposed into LDS (coalesced global, conflict-free LDS writes)
  for (int idx = tid; idx < CF * CC; idx += 256) {
    int o = idx >> 8;       // wc layout [o][c]
    int c = idx & 255;
    Wl[c * 65 + o] = wc[idx];
  }

  const int to = tid >> 5;   // 0..7  -> output group
  const int tp = tid & 31;   // 0..31 -> pixel group
  const int o0 = to << 3;

  float acc[8][8];
#pragma unroll
  for (int i = 0; i < 8; ++i)
#pragma unroll
    for (int j = 0; j < 8; ++j) acc[i][j] = 0.f;

  const float* fb = feat + (size_t)b * CF * NPIX + p0;

  for (int c0 = 0; c0 < CF; c0 += 16) {
    __syncthreads();
    // stage 16 channels x 256 pixels = 1024 float4
#pragma unroll
    for (int q = 0; q < 4; ++q) {
      int f4 = tid + q * 256;
      int row = f4 >> 6;
      int col4 = f4 & 63;
      ((float4*)Fl)[f4] =
          *(const float4*)(fb + (size_t)(c0 + row) * NPIX + col4 * 4);
    }
    __syncthreads();
#pragma unroll
    for (int cc = 0; cc < 16; ++cc) {
      float f[8], wv[8];
      float4 fa = ((const float4*)(Fl + cc * 256 + tp * 8))[0];
      float4 fbv = ((const float4*)(Fl + cc * 256 + tp * 8))[1];
      f[0] = fa.x; f[1] = fa.y; f[2] = fa.z; f[3] = fa.w;
      f[4] = fbv.x; f[5] = fbv.y; f[6] = fbv.z; f[7] = fbv.w;
      const float* wr = Wl + (c0 + cc) * 65 + o0;
#pragma unroll
      for (int i = 0; i < 8; ++i) wv[i] = wr[i];
#pragma unroll
      for (int i = 0; i < 8; ++i)
#pragma unroll
        for (int j = 0; j < 8; ++j) acc[i][j] += wv[i] * f[j];
    }
  }

  float* gb = guide + ((size_t)b * CC) * NPIX + p0 + tp * 8;
#pragma unroll
  for (int i = 0; i < 8; ++i) {
    float bias = bc[o0 + i];
    float4 v0 = {acc[i][0] + bias, acc[i][1] + bias, acc[i][2] + bias,
                 acc[i][3] + bias};
    float4 v1 = {acc[i][4] + bias, acc[i][5] + bias, acc[i][6] + bias,
                 acc[i][7] + bias};
    float* op = gb + (size_t)(o0 + i) * NPIX;
    ((float4*)op)[0] = v0;
    ((float4*)op)[1] = v1;
  }
}

// ---------- Kernel B: 3x3 conv (SAME, zero pad) + bias + softmax --------
// mask[b][kk][Y][X] = softmax_kk( sum_{c,dy,dx} guide[b][c][Y+dy-1][X+dx-1]
//                                  * we[kk][c][dy][dx] + be[kk] )
// grid: 256 blocks (4 b x 8x8 tiles of 16x16 px), block 256 threads, 1 px/thread.
__global__ __launch_bounds__(256) void k_conv_softmax(
    const float* __restrict__ guide, const float* __restrict__ we,
    const float* __restrict__ be, float* __restrict__ mask) {
  __shared__ float Gt[16 * 18 * 18];  // [i][r(18)][cl(18)]
  __shared__ float Wt[16 * 9 * 32];   // [i][tap][kk pad->32] (16B aligned rows)
  const int tid = threadIdx.x;
  const int bx = blockIdx.x;
  const int b = bx >> 6;
  const int t = bx & 63;
  const int ty0 = (t >> 3) << 4;
  const int tx0 = (t & 7) << 4;
  const int ty = tid >> 4, tx = tid & 15;
  const int Y = ty0 + ty, X = tx0 + tx;

  float acc[KK];
#pragma unroll
  for (int kk = 0; kk < KK; ++kk) acc[kk] = be[kk];

  for (int c0 = 0; c0 < CC; c0 += 16) {
    __syncthreads();
    // stage guide halo tile: 16ch x 18 x 18, zero padded
    for (int idx = tid; idx < 16 * 324; idx += 256) {
      int i = idx / 324;
      int rem = idx - i * 324;
      int r = rem / 18;
      int cl = rem - r * 18;
      int gy = ty0 - 1 + r;
      int gx = tx0 - 1 + cl;
      float v = 0.f;
      if (gy >= 0 && gy < HH && gx >= 0 && gx < WW)
        v = guide[(((size_t)b * CC + c0 + i) << 14) + (gy << 7) + gx];
      Gt[idx] = v;
    }
    // stage weights: [i][tap][kk]
    for (int idx = tid; idx < 16 * 225; idx += 256) {
      int i = idx / 225;
      int rem = idx - i * 225;
      int tap = rem / 25;
      int kk = rem - tap * 25;
      Wt[(i * 9 + tap) * 32 + kk] = we[((kk << 6) + c0 + i) * 9 + tap];
    }
    __syncthreads();
    for (int i = 0; i < 16; ++i) {
#pragma unroll
      for (int dy = 0; dy < 3; ++dy)
#pragma unroll
        for (int dx = 0; dx < 3; ++dx) {
          float g = Gt[i * 324 + (ty + dy) * 18 + (tx + dx)];
          const float* wr = Wt + (i * 9 + dy * 3 + dx) * 32;
#pragma unroll
          for (int k4 = 0; k4 < 6; ++k4) {
            float4 w4 = ((const float4*)wr)[k4];
            acc[k4 * 4 + 0] += g * w4.x;
            acc[k4 * 4 + 1] += g * w4.y;
            acc[k4 * 4 + 2] += g * w4.z;
            acc[k4 * 4 + 3] += g * w4.w;
          }
          acc[24] += g * wr[24];
        }
    }
  }

  // per-pixel softmax over 25 (all in registers)
  float m = acc[0];
#pragma unroll
  for (int kk = 1; kk < KK; ++kk) m = fmaxf(m, acc[kk]);
  float s = 0.f;
#pragma unroll
  for (int kk = 0; kk < KK; ++kk) {
    acc[kk] = __expf(acc[kk] - m);
    s += acc[kk];
  }
  float inv = 1.f / s;
  size_t base = (((size_t)b * KK) << 14) + (Y << 7) + X;
#pragma unroll
  for (int kk = 0; kk < KK; ++kk)
    mask[base + ((size_t)kk << 14)] = acc[kk] * inv;
}

// -------------------- Kernel C: CARAFE upsample -------------------------
// out[b][c][Y][X] = sum_{i,j} pred_reflectpad[b][c][Y/2+i][X/2+j] * m[i*5+j]
// grid: 256 blocks (4 b x 8x8 tiles of 16x16 hi-res px), block 256 threads.
__global__ __launch_bounds__(256) void k_carafe(
    const float* __restrict__ pred, const float* __restrict__ mask,
    float* __restrict__ out) {
  __shared__ float Pl[CP * 156];  // [c][r(12)][cl pad->13]
  const int tid = threadIdx.x;
  const int bx = blockIdx.x;
  const int b = bx >> 6;
  const int t = bx & 63;
  const int Y0 = (t >> 3) << 4;
  const int X0 = (t & 7) << 4;
  const int ty = tid >> 4, tx = tid & 15;
  const int Y = Y0 + ty, X = X0 + tx;

  // mask values for this output pixel -> registers
  float m[KK];
  size_t mb = (((size_t)b * KK) << 14) + (Y << 7) + X;
#pragma unroll
  for (int kk = 0; kk < KK; ++kk) m[kk] = mask[mb + ((size_t)kk << 14)];

  // stage all 80 channels of the reflect-padded lo-res tile (12x12 per ch)
  const int y0 = (Y0 >> 1) - 2, x0 = (X0 >> 1) - 2;
  for (int idx = tid; idx < CP * 144; idx += 256) {
    int c = idx / 144;
    int rem = idx - c * 144;
    int r = rem / 12;
    int cl = rem - r * 12;
    int ry = y0 + r;
    ry = ry < 0 ? -ry : (ry > 63 ? 126 - ry : ry);
    int rx = x0 + cl;
    rx = rx < 0 ? -rx : (rx > 63 ? 126 - rx : rx);
    Pl[c * 156 + r * 13 + cl] = pred[(((size_t)b * CP + c) << 12) + (ry << 6) + rx];
  }
  __syncthreads();

  const int ly = ty >> 1, lx = tx >> 1;
  float* ob = out + (((size_t)b * CP) << 14) + (Y << 7) + X;
  for (int c = 0; c < CP; ++c) {
    const float* P = Pl + c * 156 + ly * 13 + lx;
    float acc = 0.f;
#pragma unroll
    for (int i = 0; i < 5; ++i)
#pragma unroll
      for (int j = 0; j < 5; ++j) acc += P[i * 13 + j] * m[i * 5 + j];
    ob[(size_t)c << 14] = acc;
  }
}

extern "C" void kernel_launch(void* const* d_in, const int* in_sizes, int n_in,
                              void* d_out, int out_size, void* d_ws,
                              size_t ws_size, hipStream_t stream) {
  (void)in_sizes; (void)n_in; (void)out_size; (void)ws_size;
  const float* pred = (const float*)d_in[0];  // (4,80,64,64)
  const float* feat = (const float*)d_in[1];  // (4,256,128,128)
  const float* wc   = (const float*)d_in[2];  // (64,256)
  const float* bc   = (const float*)d_in[3];  // (64)
  const float* we   = (const float*)d_in[4];  // (25,64,3,3)
  const float* be   = (const float*)d_in[5];  // (25)
  float* out = (float*)d_out;                 // (4,80,128,128)

  float* guide = (float*)d_ws;                          // 16.78 MB
  float* mask = (float*)((char*)d_ws + (size_t)BB * CC * NPIX * 4);  // 6.55 MB

  hipLaunchKernelGGL(k_compress, dim3(256), dim3(256), 0, stream,
                     feat, wc, bc, guide);
  hipLaunchKernelGGL(k_conv_softmax, dim3(256), dim3(256), 0, stream,
                     guide, we, be, mask);
  hipLaunchKernelGGL(k_carafe, dim3(256), dim3(256), 0, stream,
                     pred, mask, out);
}

// Round 2
// 68.191 us; speedup vs baseline: 2.4226x; 2.4226x over previous
//
#include <hip/hip_runtime.h>
#include <hip/hip_bf16.h>

// Problem constants (fixed by setup_inputs)
#define BB   4
#define CF   256
#define CC   64
#define CP   80
#define HH   128   // hi-res
#define WW   128
#define KK   25
#define NPIX 16384 // 128*128

typedef __attribute__((ext_vector_type(8))) short short8v;
typedef __attribute__((ext_vector_type(4))) short short4v;
typedef __attribute__((ext_vector_type(4))) float f32x4;

static __device__ __forceinline__ short f2bf(float f) {
  __hip_bfloat16 h = __float2bfloat16(f);
  return *reinterpret_cast<short*>(&h);
}

// ---------------- prestage: weights -> bf16 in MFMA-friendly layouts ----
// wcb: [o][c]      (64 x 256)
// web: [tap][kk pad 32][c]  (9 x 32 x 64), zero for kk >= 25
__global__ __launch_bounds__(256) void k_prestage(
    const float* __restrict__ wc, const float* __restrict__ we,
    short* __restrict__ wcb, short* __restrict__ web) {
  int idx = blockIdx.x * 256 + threadIdx.x;
  if (idx < CC * CF) wcb[idx] = f2bf(wc[idx]);
  int j = idx - CC * CF;
  if (j >= 0 && j < 9 * 32 * 64) {
    int tap = j >> 11;
    int kk = (j >> 6) & 31;
    int c = j & 63;
    float v = (kk < KK) ? we[(kk * 64 + c) * 9 + tap] : 0.f;
    web[j] = f2bf(v);
  }
}

// ---------------- Kernel A: compress via bf16 MFMA ----------------------
// guide[b][y][x][c] (bf16) = sum_c' feat[b][c'][y][x] * wc[c][c'] + bc[c]
// grid 512 = 4 b x 128 y-rows; block 256 (4 waves); per block: 64 out-ch x 128 px.
// Wave w: px rows (n-frags) {2w, 2w+1} (16 px each); 4 m-frags (64 ch).
__global__ __launch_bounds__(256) void k_compress_mfma(
    const float* __restrict__ feat, const short* __restrict__ wcb,
    const float* __restrict__ bc, short* __restrict__ guide) {
  __shared__ short Bl[128 * 72];  // [px][c-chunk 64, stride 72]
  const int tid = threadIdx.x;
  const int b = blockIdx.x >> 7;
  const int y = blockIdx.x & 127;
  const int wave = tid >> 6;
  const int l = tid & 63;
  const int l15 = l & 15, lh = l >> 4;

  f32x4 acc[4][2];
#pragma unroll
  for (int m = 0; m < 4; ++m)
#pragma unroll
    for (int n = 0; n < 2; ++n) acc[m][n] = (f32x4){0.f, 0.f, 0.f, 0.f};

  const float* fb = feat + (size_t)b * CF * NPIX + y * WW;
  const int px_s = tid & 127;
  const int c_s = (tid >> 7) * 32;

  for (int c0 = 0; c0 < CF; c0 += 64) {
    if (c0) __syncthreads();
    float v[32];
#pragma unroll
    for (int i = 0; i < 32; ++i)
      v[i] = fb[(size_t)(c0 + c_s + i) * NPIX + px_s];
    short8v hv[4];
#pragma unroll
    for (int q = 0; q < 4; ++q)
#pragma unroll
      for (int e = 0; e < 8; ++e) hv[q][e] = f2bf(v[q * 8 + e]);
    short8v* dst = (short8v*)(Bl + px_s * 72 + c_s);
#pragma unroll
    for (int q = 0; q < 4; ++q) dst[q] = hv[q];
    __syncthreads();
#pragma unroll
    for (int ks = 0; ks < 64; ks += 32) {
      short8v a[4], bfr[2];
#pragma unroll
      for (int m = 0; m < 4; ++m)
        a[m] = *(const short8v*)(wcb + (m * 16 + l15) * CF + c0 + ks + lh * 8);
#pragma unroll
      for (int n = 0; n < 2; ++n) {
        int px = (wave * 2 + n) * 16 + l15;
        bfr[n] = *(const short8v*)(Bl + px * 72 + ks + lh * 8);
      }
#pragma unroll
      for (int m = 0; m < 4; ++m)
#pragma unroll
        for (int n = 0; n < 2; ++n)
          acc[m][n] = __builtin_amdgcn_mfma_f32_16x16x32_bf16(
              a[m], bfr[n], acc[m][n], 0, 0, 0);
    }
  }

  // epilogue: +bias, cvt bf16, store [b][y][x][c]
#pragma unroll
  for (int m = 0; m < 4; ++m)
#pragma unroll
    for (int n = 0; n < 2; ++n) {
      int px = (wave * 2 + n) * 16 + l15;
      short4v o;
#pragma unroll
      for (int r = 0; r < 4; ++r) {
        int c = m * 16 + lh * 4 + r;
        o[r] = f2bf(acc[m][n][r] + bc[c]);
      }
      *(short4v*)(guide + ((size_t)((b * HH + y) * WW + px)) * CC + m * 16 +
                  lh * 4) = o;
    }
}

// ---------------- Kernel B: conv3x3 + bias + softmax via MFMA -----------
// 9 shifted 1x1 GEMMs (one per tap), M=25(pad32) kk, K=64 c, N=px, same acc.
// grid 512 = 4 b x (16 y-tiles of 8) x (8 x-tiles of 16); block 256 (4 waves).
__global__ __launch_bounds__(256) void k_conv_mfma(
    const short* __restrict__ guide, const short* __restrict__ web,
    const float* __restrict__ be, float* __restrict__ mask) {
  __shared__ short Gl[10 * 18 * 72];  // [y'][x'][c], stride 72
  const int tid = threadIdx.x;
  const int b = blockIdx.x >> 7;
  const int t = blockIdx.x & 127;
  const int y0 = (t >> 3) << 3;
  const int x0 = (t & 7) << 4;
  const int wave = tid >> 6;
  const int l = tid & 63;
  const int l15 = l & 15, lh = l >> 4;

  // stage halo tile (zero-pad at borders), 8 bf16 per slot
  for (int idx = tid; idx < 10 * 18 * 8; idx += 256) {
    int yp = idx / 144;
    int rem = idx - yp * 144;
    int xp = rem >> 3;
    int cq = (rem & 7) << 3;
    int gy = y0 - 1 + yp, gx = x0 - 1 + xp;
    short8v v = {0, 0, 0, 0, 0, 0, 0, 0};
    if (gy >= 0 && gy < HH && gx >= 0 && gx < WW)
      v = *(const short8v*)(guide + ((size_t)((b * HH + gy) * WW + gx)) * CC + cq);
    *(short8v*)(Gl + (yp * 18 + xp) * 72 + cq) = v;
  }
  __syncthreads();

  f32x4 acc[2][2];
#pragma unroll
  for (int m = 0; m < 2; ++m)
#pragma unroll
    for (int n = 0; n < 2; ++n) acc[m][n] = (f32x4){0.f, 0.f, 0.f, 0.f};

#pragma unroll
  for (int tap = 0; tap < 9; ++tap) {
    const int dy = tap / 3, dx = tap - dy * 3;
#pragma unroll
    for (int ks = 0; ks < 64; ks += 32) {
      short8v a0 = *(const short8v*)(web + (tap * 32 + l15) * 64 + ks + lh * 8);
      short8v a1 =
          *(const short8v*)(web + (tap * 32 + 16 + l15) * 64 + ks + lh * 8);
#pragma unroll
      for (int n = 0; n < 2; ++n) {
        int row = wave * 2 + n;
        short8v bf = *(const short8v*)(Gl + ((row + dy) * 18 + l15 + dx) * 72 +
                                       ks + lh * 8);
        acc[0][n] =
            __builtin_amdgcn_mfma_f32_16x16x32_bf16(a0, bf, acc[0][n], 0, 0, 0);
        acc[1][n] =
            __builtin_amdgcn_mfma_f32_16x16x32_bf16(a1, bf, acc[1][n], 0, 0, 0);
      }
    }
  }

  // bias + softmax over kk (25 values live in 4 lanes: xor 16, 32) + store
#pragma unroll
  for (int n = 0; n < 2; ++n) {
    int row = wave * 2 + n;
    float v[8];
#pragma unroll
    for (int m = 0; m < 2; ++m)
#pragma unroll
      for (int r = 0; r < 4; ++r) {
        int kk = m * 16 + lh * 4 + r;
        v[m * 4 + r] = (kk < KK) ? (acc[m][n][r] + be[kk]) : -1e30f;
      }
    float mx = v[0];
#pragma unroll
    for (int i = 1; i < 8; ++i) mx = fmaxf(mx, v[i]);
    mx = fmaxf(mx, __shfl_xor(mx, 16));
    mx = fmaxf(mx, __shfl_xor(mx, 32));
    float s = 0.f;
#pragma unroll
    for (int i = 0; i < 8; ++i) {
      v[i] = __expf(v[i] - mx);
      s += v[i];
    }
    s += __shfl_xor(s, 16);
    s += __shfl_xor(s, 32);
    float inv = 1.f / s;
    size_t base = (((size_t)b * KK) << 14) + ((size_t)(y0 + row) << 7) + x0 + l15;
#pragma unroll
    for (int m = 0; m < 2; ++m)
#pragma unroll
      for (int r = 0; r < 4; ++r) {
        int kk = m * 16 + lh * 4 + r;
        if (kk < KK) mask[base + ((size_t)kk << 14)] = v[m * 4 + r] * inv;
      }
  }
}

// -------------------- Kernel C: CARAFE upsample (unchanged) -------------
__global__ __launch_bounds__(256) void k_carafe(
    const float* __restrict__ pred, const float* __restrict__ mask,
    float* __restrict__ out) {
  __shared__ float Pl[CP * 156];  // [c][r(12)][cl pad->13]
  const int tid = threadIdx.x;
  const int bx = blockIdx.x;
  const int b = bx >> 6;
  const int t = bx & 63;
  const int Y0 = (t >> 3) << 4;
  const int X0 = (t & 7) << 4;
  const int ty = tid >> 4, tx = tid & 15;
  const int Y = Y0 + ty, X = X0 + tx;

  float m[KK];
  size_t mb = (((size_t)b * KK) << 14) + (Y << 7) + X;
#pragma unroll
  for (int kk = 0; kk < KK; ++kk) m[kk] = mask[mb + ((size_t)kk << 14)];

  const int y0 = (Y0 >> 1) - 2, x0 = (X0 >> 1) - 2;
  for (int idx = tid; idx < CP * 144; idx += 256) {
    int c = idx / 144;
    int rem = idx - c * 144;
    int r = rem / 12;
    int cl = rem - r * 12;
    int ry = y0 + r;
    ry = ry < 0 ? -ry : (ry > 63 ? 126 - ry : ry);
    int rx = x0 + cl;
    rx = rx < 0 ? -rx : (rx > 63 ? 126 - rx : rx);
    Pl[c * 156 + r * 13 + cl] = pred[(((size_t)b * CP + c) << 12) + (ry << 6) + rx];
  }
  __syncthreads();

  const int ly = ty >> 1, lx = tx >> 1;
  float* ob = out + (((size_t)b * CP) << 14) + (Y << 7) + X;
  for (int c = 0; c < CP; ++c) {
    const float* P = Pl + c * 156 + ly * 13 + lx;
    float acc = 0.f;
#pragma unroll
    for (int i = 0; i < 5; ++i)
#pragma unroll
      for (int j = 0; j < 5; ++j) acc += P[i * 13 + j] * m[i * 5 + j];
    ob[(size_t)c << 14] = acc;
  }
}

extern "C" void kernel_launch(void* const* d_in, const int* in_sizes, int n_in,
                              void* d_out, int out_size, void* d_ws,
                              size_t ws_size, hipStream_t stream) {
  (void)in_sizes; (void)n_in; (void)out_size; (void)ws_size;
  const float* pred = (const float*)d_in[0];  // (4,80,64,64)
  const float* feat = (const float*)d_in[1];  // (4,256,128,128)
  const float* wc   = (const float*)d_in[2];  // (64,256)
  const float* bc   = (const float*)d_in[3];  // (64)
  const float* we   = (const float*)d_in[4];  // (25,64,3,3)
  const float* be   = (const float*)d_in[5];  // (25)
  float* out = (float*)d_out;                 // (4,80,128,128)

  char* ws = (char*)d_ws;
  short* guide = (short*)ws;                           // 8,388,608 B (bf16)
  float* mask  = (float*)(ws + 8388608);               // 6,553,600 B
  short* wcb   = (short*)(ws + 8388608 + 6553600);     // 32,768 B
  short* web   = (short*)(ws + 8388608 + 6553600 + 32768);  // 36,864 B

  hipLaunchKernelGGL(k_prestage, dim3(136), dim3(256), 0, stream, wc, we, wcb, web);
  hipLaunchKernelGGL(k_compress_mfma, dim3(512), dim3(256), 0, stream,
                     feat, wcb, bc, guide);
  hipLaunchKernelGGL(k_conv_mfma, dim3(512), dim3(256), 0, stream,
                     guide, web, be, mask);
  hipLaunchKernelGGL(k_carafe, dim3(256), dim3(256), 0, stream,
                     pred, mask, out);
}

// Round 3
// 63.140 us; speedup vs baseline: 2.6164x; 1.0800x over previous
//
#include <hip/hip_runtime.h>
#include <hip/hip_bf16.h>

// Problem constants (fixed by setup_inputs)
#define BB   4
#define CF   256
#define CC   64
#define CP   80
#define HH   128   // hi-res
#define WW   128
#define KK   25
#define NPIX 16384 // 128*128

typedef __attribute__((ext_vector_type(8))) short short8v;
typedef __attribute__((ext_vector_type(4))) short short4v;
typedef __attribute__((ext_vector_type(4))) float f32x4;

static __device__ __forceinline__ short f2bf(float f) {
  __hip_bfloat16 h = __float2bfloat16(f);
  return *reinterpret_cast<short*>(&h);
}
static __device__ __forceinline__ float bf2f(short s) {
  unsigned u = ((unsigned)(unsigned short)s) << 16;
  return __uint_as_float(u);
}

// ---------------- prestage: weights -> bf16 in MFMA-friendly layouts ----
// wcb: [o][c]      (64 x 256)
// web: [tap][kk pad 32][c]  (9 x 32 x 64), zero for kk >= 25
__global__ __launch_bounds__(256) void k_prestage(
    const float* __restrict__ wc, const float* __restrict__ we,
    short* __restrict__ wcb, short* __restrict__ web) {
  int idx = blockIdx.x * 256 + threadIdx.x;
  if (idx < CC * CF) wcb[idx] = f2bf(wc[idx]);
  int j = idx - CC * CF;
  if (j >= 0 && j < 9 * 32 * 64) {
    int tap = j >> 11;
    int kk = (j >> 6) & 31;
    int c = j & 63;
    float v = (kk < KK) ? we[(kk * 64 + c) * 9 + tap] : 0.f;
    web[j] = f2bf(v);
  }
}

// ---------------- Kernel A: compress via bf16 MFMA ----------------------
// guide[b][y][x][c] (bf16) = sum_c' feat[b][c'][y][x] * wc[c][c'] + bc[c]
__global__ __launch_bounds__(256) void k_compress_mfma(
    const float* __restrict__ feat, const short* __restrict__ wcb,
    const float* __restrict__ bc, short* __restrict__ guide) {
  __shared__ short Bl[128 * 72];  // [px][c-chunk 64, stride 72]
  const int tid = threadIdx.x;
  const int b = blockIdx.x >> 7;
  const int y = blockIdx.x & 127;
  const int wave = tid >> 6;
  const int l = tid & 63;
  const int l15 = l & 15, lh = l >> 4;

  f32x4 acc[4][2];
#pragma unroll
  for (int m = 0; m < 4; ++m)
#pragma unroll
    for (int n = 0; n < 2; ++n) acc[m][n] = (f32x4){0.f, 0.f, 0.f, 0.f};

  const float* fb = feat + (size_t)b * CF * NPIX + y * WW;
  const int px_s = tid & 127;
  const int c_s = (tid >> 7) * 32;

  for (int c0 = 0; c0 < CF; c0 += 64) {
    if (c0) __syncthreads();
    float v[32];
#pragma unroll
    for (int i = 0; i < 32; ++i)
      v[i] = fb[(size_t)(c0 + c_s + i) * NPIX + px_s];
    short8v hv[4];
#pragma unroll
    for (int q = 0; q < 4; ++q)
#pragma unroll
      for (int e = 0; e < 8; ++e) hv[q][e] = f2bf(v[q * 8 + e]);
    short8v* dst = (short8v*)(Bl + px_s * 72 + c_s);
#pragma unroll
    for (int q = 0; q < 4; ++q) dst[q] = hv[q];
    __syncthreads();
#pragma unroll
    for (int ks = 0; ks < 64; ks += 32) {
      short8v a[4], bfr[2];
#pragma unroll
      for (int m = 0; m < 4; ++m)
        a[m] = *(const short8v*)(wcb + (m * 16 + l15) * CF + c0 + ks + lh * 8);
#pragma unroll
      for (int n = 0; n < 2; ++n) {
        int px = (wave * 2 + n) * 16 + l15;
        bfr[n] = *(const short8v*)(Bl + px * 72 + ks + lh * 8);
      }
#pragma unroll
      for (int m = 0; m < 4; ++m)
#pragma unroll
        for (int n = 0; n < 2; ++n)
          acc[m][n] = __builtin_amdgcn_mfma_f32_16x16x32_bf16(
              a[m], bfr[n], acc[m][n], 0, 0, 0);
    }
  }

  // epilogue: +bias, cvt bf16, store [b][y][x][c]
#pragma unroll
  for (int m = 0; m < 4; ++m)
#pragma unroll
    for (int n = 0; n < 2; ++n) {
      int px = (wave * 2 + n) * 16 + l15;
      short4v o;
#pragma unroll
      for (int r = 0; r < 4; ++r) {
        int c = m * 16 + lh * 4 + r;
        o[r] = f2bf(acc[m][n][r] + bc[c]);
      }
      *(short4v*)(guide + ((size_t)((b * HH + y) * WW + px)) * CC + m * 16 +
                  lh * 4) = o;
    }
}

// ---------------- Kernel B: conv3x3 + bias + softmax via MFMA -----------
// Output: maskb[b][Y][X][32] bf16 (kk-contiguous per pixel, pad 32)
__global__ __launch_bounds__(256) void k_conv_mfma(
    const short* __restrict__ guide, const short* __restrict__ web,
    const float* __restrict__ be, short* __restrict__ maskb) {
  __shared__ short Gl[10 * 18 * 72];  // [y'][x'][c], stride 72
  const int tid = threadIdx.x;
  const int b = blockIdx.x >> 7;
  const int t = blockIdx.x & 127;
  const int y0 = (t >> 3) << 3;
  const int x0 = (t & 7) << 4;
  const int wave = tid >> 6;
  const int l = tid & 63;
  const int l15 = l & 15, lh = l >> 4;

  // stage halo tile (zero-pad at borders), 8 bf16 per slot
  for (int idx = tid; idx < 10 * 18 * 8; idx += 256) {
    int yp = idx / 144;
    int rem = idx - yp * 144;
    int xp = rem >> 3;
    int cq = (rem & 7) << 3;
    int gy = y0 - 1 + yp, gx = x0 - 1 + xp;
    short8v v = {0, 0, 0, 0, 0, 0, 0, 0};
    if (gy >= 0 && gy < HH && gx >= 0 && gx < WW)
      v = *(const short8v*)(guide + ((size_t)((b * HH + gy) * WW + gx)) * CC + cq);
    *(short8v*)(Gl + (yp * 18 + xp) * 72 + cq) = v;
  }
  __syncthreads();

  f32x4 acc[2][2];
#pragma unroll
  for (int m = 0; m < 2; ++m)
#pragma unroll
    for (int n = 0; n < 2; ++n) acc[m][n] = (f32x4){0.f, 0.f, 0.f, 0.f};

#pragma unroll
  for (int tap = 0; tap < 9; ++tap) {
    const int dy = tap / 3, dx = tap - dy * 3;
#pragma unroll
    for (int ks = 0; ks < 64; ks += 32) {
      short8v a0 = *(const short8v*)(web + (tap * 32 + l15) * 64 + ks + lh * 8);
      short8v a1 =
          *(const short8v*)(web + (tap * 32 + 16 + l15) * 64 + ks + lh * 8);
#pragma unroll
      for (int n = 0; n < 2; ++n) {
        int row = wave * 2 + n;
        short8v bf = *(const short8v*)(Gl + ((row + dy) * 18 + l15 + dx) * 72 +
                                       ks + lh * 8);
        acc[0][n] =
            __builtin_amdgcn_mfma_f32_16x16x32_bf16(a0, bf, acc[0][n], 0, 0, 0);
        acc[1][n] =
            __builtin_amdgcn_mfma_f32_16x16x32_bf16(a1, bf, acc[1][n], 0, 0, 0);
      }
    }
  }

  // bias + softmax over kk (25 values live in 4 lanes: xor 16, 32) + store
#pragma unroll
  for (int n = 0; n < 2; ++n) {
    int row = wave * 2 + n;
    float v[8];
#pragma unroll
    for (int m = 0; m < 2; ++m)
#pragma unroll
      for (int r = 0; r < 4; ++r) {
        int kk = m * 16 + lh * 4 + r;
        v[m * 4 + r] = (kk < KK) ? (acc[m][n][r] + be[kk]) : -1e30f;
      }
    float mx = v[0];
#pragma unroll
    for (int i = 1; i < 8; ++i) mx = fmaxf(mx, v[i]);
    mx = fmaxf(mx, __shfl_xor(mx, 16));
    mx = fmaxf(mx, __shfl_xor(mx, 32));
    float s = 0.f;
#pragma unroll
    for (int i = 0; i < 8; ++i) {
      v[i] = __expf(v[i] - mx);
      s += v[i];
    }
    s += __shfl_xor(s, 16);
    s += __shfl_xor(s, 32);
    float inv = 1.f / s;
    size_t base = ((size_t)((b * HH + y0 + row) * WW + x0 + l15)) << 5;
#pragma unroll
    for (int m = 0; m < 2; ++m)
#pragma unroll
      for (int r = 0; r < 4; ++r) {
        int kk = m * 16 + lh * 4 + r;
        if (kk < KK) maskb[base + kk] = f2bf(v[m * 4 + r] * inv);
      }
  }
}

// -------------------- Kernel C: CARAFE upsample v2 ----------------------
// up=2 => a 2x2 output quad shares the SAME 5x5 lo-res patch.
// grid 1024 = 4 b x 16x16 tiles of 8x8 hi-px. block 256 = 16 quads x 16
// ch-groups (5 ch). Pred tile (80ch x 8x8 lo, reflect) in LDS; quad masks
// (4 px x 25) held in registers, loaded from bf16 [b][Y][X][32].
__global__ __launch_bounds__(256) void k_carafe2(
    const float* __restrict__ pred, const short* __restrict__ maskb,
    float* __restrict__ out) {
  __shared__ float Pl[CP * 72];  // [c][r(8)][cl pad->9]
  const int tid = threadIdx.x;
  const int bx = blockIdx.x;
  const int b = bx >> 8;
  const int t = bx & 255;
  const int Y0 = (t >> 4) << 3;
  const int X0 = (t & 15) << 3;
  const int q = tid & 15;   // quad id in 4x4 quad grid
  const int g = tid >> 4;   // channel group (5 ch)
  const int qy = q >> 2, qx = q & 3;

  // stage pred: 80 ch x 8 x 8 lo-res (rows Y0/2-2 ..), reflect-padded
  const int y0 = (Y0 >> 1) - 2, x0 = (X0 >> 1) - 2;
  for (int idx = tid; idx < CP * 64; idx += 256) {
    int c = idx >> 6;
    int r = (idx >> 3) & 7;
    int cl = idx & 7;
    int ry = y0 + r;
    ry = ry < 0 ? -ry : (ry > 63 ? 126 - ry : ry);
    int rx = x0 + cl;
    rx = rx < 0 ? -rx : (rx > 63 ? 126 - rx : rx);
    Pl[c * 72 + r * 9 + cl] =
        pred[(((size_t)b * CP + c) << 12) + (ry << 6) + rx];
  }

  // masks for my quad's 4 px -> 100 f32 regs (static indexing throughout)
  const int Yq = Y0 + qy * 2, Xq = X0 + qx * 2;
  float m[4][KK];
#pragma unroll
  for (int dy = 0; dy < 2; ++dy)
#pragma unroll
    for (int dx = 0; dx < 2; ++dx) {
      const short8v* mp =
          (const short8v*)(maskb +
                           ((size_t)((b * HH + Yq + dy) * WW + Xq + dx) << 5));
#pragma unroll
      for (int v8 = 0; v8 < 4; ++v8) {
        short8v mv = mp[v8];
#pragma unroll
        for (int e = 0; e < 8; ++e) {
          int kk = v8 * 8 + e;
          if (kk < KK) m[dy * 2 + dx][kk] = bf2f(mv[e]);
        }
      }
    }
  __syncthreads();

  float acc[5][4];
#pragma unroll
  for (int cc = 0; cc < 5; ++cc)
#pragma unroll
    for (int px = 0; px < 4; ++px) acc[cc][px] = 0.f;

  const float* P0 = Pl + (g * 5) * 72 + qy * 9 + qx;
#pragma unroll
  for (int cc = 0; cc < 5; ++cc) {
    float p[KK];
#pragma unroll
    for (int i = 0; i < 5; ++i)
#pragma unroll
      for (int j = 0; j < 5; ++j) p[i * 5 + j] = P0[cc * 72 + i * 9 + j];
#pragma unroll
    for (int px = 0; px < 4; ++px) {
      float a = 0.f;
#pragma unroll
      for (int kk = 0; kk < KK; ++kk) a += p[kk] * m[px][kk];
      acc[cc][px] = a;
    }
  }

  // store 5 ch x 4 px
#pragma unroll
  for (int cc = 0; cc < 5; ++cc) {
    float* ob = out + (((size_t)(b * CP + g * 5 + cc)) << 14);
#pragma unroll
    for (int dy = 0; dy < 2; ++dy)
#pragma unroll
      for (int dx = 0; dx < 2; ++dx)
        ob[(Yq + dy) * WW + Xq + dx] = acc[cc][dy * 2 + dx];
  }
}

extern "C" void kernel_launch(void* const* d_in, const int* in_sizes, int n_in,
                              void* d_out, int out_size, void* d_ws,
                              size_t ws_size, hipStream_t stream) {
  (void)in_sizes; (void)n_in; (void)out_size; (void)ws_size;
  const float* pred = (const float*)d_in[0];  // (4,80,64,64)
  const float* feat = (const float*)d_in[1];  // (4,256,128,128)
  const float* wc   = (const float*)d_in[2];  // (64,256)
  const float* bc   = (const float*)d_in[3];  // (64)
  const float* we   = (const float*)d_in[4];  // (25,64,3,3)
  const float* be   = (const float*)d_in[5];  // (25)
  float* out = (float*)d_out;                 // (4,80,128,128)

  char* ws = (char*)d_ws;
  short* guide = (short*)ws;                            // 8,388,608 B (bf16)
  short* maskb = (short*)(ws + 8388608);                // 4,194,304 B (bf16)
  short* wcb   = (short*)(ws + 8388608 + 4194304);      // 32,768 B
  short* web   = (short*)(ws + 8388608 + 4194304 + 32768);  // 36,864 B

  hipLaunchKernelGGL(k_prestage, dim3(136), dim3(256), 0, stream, wc, we, wcb, web);
  hipLaunchKernelGGL(k_compress_mfma, dim3(512), dim3(256), 0, stream,
                     feat, wcb, bc, guide);
  hipLaunchKernelGGL(k_conv_mfma, dim3(512), dim3(256), 0, stream,
                     guide, web, be, maskb);
  hipLaunchKernelGGL(k_carafe2, dim3(1024), dim3(256), 0, stream,
                     pred, maskb, out);
}

// Round 4
// 58.563 us; speedup vs baseline: 2.8209x; 1.0782x over previous
//
#include <hip/hip_runtime.h>
#include <hip/hip_bf16.h>

// Problem constants (fixed by setup_inputs)
#define BB   4
#define CF   256
#define CC   64
#define CP   80
#define HH   128   // hi-res
#define WW   128
#define KK   25
#define NPIX 16384 // 128*128

typedef __attribute__((ext_vector_type(8))) short short8v;
typedef __attribute__((ext_vector_type(4))) short short4v;
typedef __attribute__((ext_vector_type(4))) float f32x4;
typedef __attribute__((ext_vector_type(2))) float f32x2;

static __device__ __forceinline__ short f2bf(float f) {
  __hip_bfloat16 h = __float2bfloat16(f);
  return *reinterpret_cast<short*>(&h);
}

// =================== K1: compress (1x1 conv) via bf16 MFMA ==============
// guide[b][y][x][c] bf16 = sum_c' feat[b][c'][y][x] * wc[c][c'] + bc[c]
// grid 1024 = 4 b x 128 y x 2 x-halves (64 px). block 256 (4 waves).
// wc converted per-block into LDS in MFMA-fragment order (conflict-free).
// Also distributes the we->web bf16 conversion across blocks 0..71.
__global__ __launch_bounds__(256) void k_compress(
    const float* __restrict__ feat, const float* __restrict__ wc,
    const float* __restrict__ bc, const float* __restrict__ we,
    short* __restrict__ guide, short* __restrict__ web) {
  __shared__ short Al[32 * 520];  // [(cblk*4+lh)][o(64)*8], pad 512->520
  __shared__ short Bl[64 * 72];   // [px][c 0..63], stride 72
  const int tid = threadIdx.x;
  const int bx = blockIdx.x;
  const int b = bx >> 8;
  const int y = (bx >> 1) & 127;
  const int x0 = (bx & 1) << 6;

  // distributed web prestage: web[tap][kk pad32][c], zero for kk>=25
  {
    int j = bx * 256 + tid;
    if (j < 9 * 32 * 64) {
      int tap = j >> 11, kk = (j >> 6) & 31, c = j & 63;
      float v = (kk < KK) ? we[(kk * 64 + c) * 9 + tap] : 0.f;
      web[j] = f2bf(v);
    }
  }

  // convert wc (64x256 f32) -> Al in fragment order:
  // Al[(cblk*4+lh)*520 + o*8 + e] = bf16(wc[o][cblk*32 + lh*8 + e])
#pragma unroll
  for (int t = 0; t < 8; ++t) {
    int idx = tid + t * 256;  // 0..2047
    int o = idx >> 5, c8 = idx & 31;
    const f32x4* src = (const f32x4*)(wc + o * CF + c8 * 8);
    f32x4 v0 = src[0], v1 = src[1];
    short8v h;
    h[0] = f2bf(v0.x); h[1] = f2bf(v0.y); h[2] = f2bf(v0.z); h[3] = f2bf(v0.w);
    h[4] = f2bf(v1.x); h[5] = f2bf(v1.y); h[6] = f2bf(v1.z); h[7] = f2bf(v1.w);
    int cblk = c8 >> 2, lh4 = c8 & 3;
    *(short8v*)(Al + (cblk * 4 + lh4) * 520 + o * 8) = h;
  }

  const int wave = tid >> 6, l = tid & 63;
  const int l15 = l & 15, lh = l >> 4;
  const int px_s = tid & 63;          // staging pixel
  const int c_s = (tid >> 6) << 4;    // staging channel offset (16/wave)
  const float* fb = feat + (size_t)b * CF * NPIX + y * WW + x0;

  f32x4 acc[4];
#pragma unroll
  for (int m = 0; m < 4; ++m) acc[m] = (f32x4){0.f, 0.f, 0.f, 0.f};

  for (int c0 = 0; c0 < CF; c0 += 64) {
    if (c0) __syncthreads();
    float v[16];
#pragma unroll
    for (int i = 0; i < 16; ++i)
      v[i] = fb[(size_t)(c0 + c_s + i) * NPIX + px_s];
    short8v h0, h1;
#pragma unroll
    for (int e = 0; e < 8; ++e) { h0[e] = f2bf(v[e]); h1[e] = f2bf(v[8 + e]); }
    *(short8v*)(Bl + px_s * 72 + c_s) = h0;
    *(short8v*)(Bl + px_s * 72 + c_s + 8) = h1;
    __syncthreads();  // Bl (and, first pass, Al) visible
#pragma unroll
    for (int ks = 0; ks < 64; ks += 32) {
      const int cblk = (c0 + ks) >> 5;
      short8v bfr = *(const short8v*)(Bl + (wave * 16 + l15) * 72 + ks + lh * 8);
#pragma unroll
      for (int m = 0; m < 4; ++m) {
        short8v a = *(const short8v*)(Al + (cblk * 4 + lh) * 520 +
                                      (m * 16 + l15) * 8);
        acc[m] = __builtin_amdgcn_mfma_f32_16x16x32_bf16(a, bfr, acc[m], 0, 0, 0);
      }
    }
  }

  // epilogue: +bias, cvt bf16, store [b][y][x][c]
  const int px = wave * 16 + l15;
  short* gb = guide + ((size_t)((b * HH + y) * WW + x0 + px)) * CC;
#pragma unroll
  for (int m = 0; m < 4; ++m) {
    short4v o;
#pragma unroll
    for (int r = 0; r < 4; ++r) {
      int c = m * 16 + lh * 4 + r;
      o[r] = f2bf(acc[m][r] + bc[c]);
    }
    *(short4v*)(gb + m * 16 + lh * 4) = o;
  }
}

// ======= K2: conv3x3 + bias + softmax + CARAFE, fused per 8x8 tile ======
// grid 1024 = 4 b x 16x16 tiles of 8x8 hi-px. block 256 (4 waves).
// Phase 1: conv via MFMA (M=32 kk, K=64 c, N=64 px), softmax -> Ml (f32 LDS).
// Phase 2: carafe: Pl (pred reflect tile) overwrites Gl region; 16 quads x
// 16 ch-groups of 5; quad masks in registers.
__global__ __launch_bounds__(256) void k_conv_carafe(
    const short* __restrict__ guide, const short* __restrict__ web,
    const float* __restrict__ be, const float* __restrict__ pred,
    float* __restrict__ out) {
  __shared__ char smem[23040 + 7168];
  short* Gl = (short*)smem;             // [10][10][72] = 14400 B
  float* Pl = (float*)smem;             // [80][8][9]   = 23040 B (reuses Gl)
  float* Ml = (float*)(smem + 23040);   // [64][28]     = 7168 B
  const int tid = threadIdx.x;
  const int bx = blockIdx.x;
  const int b = bx >> 8;
  const int t = bx & 255;
  const int y0 = (t >> 4) << 3, x0 = (t & 15) << 3;
  const int wave = tid >> 6, l = tid & 63;
  const int l15 = l & 15, lh = l >> 4;

  // ---- stage guide halo tile (zero-pad) ----
  for (int idx = tid; idx < 10 * 10 * 8; idx += 256) {
    int yp = idx / 80;
    int rem = idx - yp * 80;
    int xp = rem >> 3, cq = (rem & 7) << 3;
    int gy = y0 - 1 + yp, gx = x0 - 1 + xp;
    short8v v = {0, 0, 0, 0, 0, 0, 0, 0};
    if (gy >= 0 && gy < HH && gx >= 0 && gx < WW)
      v = *(const short8v*)(guide + ((size_t)((b * HH + gy) * WW + gx)) * CC + cq);
    *(short8v*)(Gl + (yp * 10 + xp) * 72 + cq) = v;
  }
  __syncthreads();

  // ---- conv MFMA: px = wave*16 + l15 -> (row, col) in 8x8 tile ----
  const int r_ = wave * 2 + (l15 >> 3);  // tile row 0..7
  const int cx = l15 & 7;                // tile col 0..7
  f32x4 acc0 = {0.f, 0.f, 0.f, 0.f}, acc1 = {0.f, 0.f, 0.f, 0.f};
#pragma unroll
  for (int tap = 0; tap < 9; ++tap) {
    const int dy = tap / 3, dx = tap - dy * 3;
#pragma unroll
    for (int ks = 0; ks < 64; ks += 32) {
      short8v a0 = *(const short8v*)(web + (tap * 32 + l15) * 64 + ks + lh * 8);
      short8v a1 =
          *(const short8v*)(web + (tap * 32 + 16 + l15) * 64 + ks + lh * 8);
      short8v bf = *(const short8v*)(Gl + ((r_ + dy) * 10 + cx + dx) * 72 +
                                     ks + lh * 8);
      acc0 = __builtin_amdgcn_mfma_f32_16x16x32_bf16(a0, bf, acc0, 0, 0, 0);
      acc1 = __builtin_amdgcn_mfma_f32_16x16x32_bf16(a1, bf, acc1, 0, 0, 0);
    }
  }

  // ---- bias + softmax over kk (25 vals in 4 lanes: xor 16,32) -> Ml ----
  {
    float sv[8];
#pragma unroll
    for (int r = 0; r < 4; ++r) {
      int kk0 = lh * 4 + r;            // 0..15, always < 25
      sv[r] = acc0[r] + be[kk0];
      int kk1 = 16 + lh * 4 + r;       // 16..31
      sv[4 + r] = (kk1 < KK) ? (acc1[r] + be[kk1]) : -1e30f;
    }
    float mx = sv[0];
#pragma unroll
    for (int i = 1; i < 8; ++i) mx = fmaxf(mx, sv[i]);
    mx = fmaxf(mx, __shfl_xor(mx, 16));
    mx = fmaxf(mx, __shfl_xor(mx, 32));
    float s = 0.f;
#pragma unroll
    for (int i = 0; i < 8; ++i) {
      sv[i] = __expf(sv[i] - mx);
      s += sv[i];
    }
    s += __shfl_xor(s, 16);
    s += __shfl_xor(s, 32);
    float inv = 1.f / s;
    int pxm = wave * 16 + l15;  // == r_*8 + cx
#pragma unroll
    for (int r = 0; r < 4; ++r) {
      Ml[pxm * 28 + lh * 4 + r] = sv[r] * inv;
      int kk1 = 16 + lh * 4 + r;
      if (kk1 < KK) Ml[pxm * 28 + kk1] = sv[4 + r] * inv;
    }
  }
  __syncthreads();  // Ml complete; Gl no longer needed

  // ---- stage Pl: 80 ch x 8x8 lo-res reflect-padded tile ----
  const int ylo = (y0 >> 1) - 2, xlo = (x0 >> 1) - 2;
  for (int idx = tid; idx < CP * 64; idx += 256) {
    int c = idx >> 6, r = (idx >> 3) & 7, cl = idx & 7;
    int ry = ylo + r;
    ry = ry < 0 ? -ry : (ry > 63 ? 126 - ry : ry);
    int rx = xlo + cl;
    rx = rx < 0 ? -rx : (rx > 63 ? 126 - rx : rx);
    Pl[c * 72 + r * 9 + cl] = pred[(((size_t)b * CP + c) << 12) + (ry << 6) + rx];
  }

  // ---- quad masks -> registers (reads Ml; no overlap with Pl region) ----
  const int q = tid & 15, g = tid >> 4;  // quad, channel-group(5)
  const int qy = q >> 2, qx = q & 3;
  float m[4][KK];
#pragma unroll
  for (int dy = 0; dy < 2; ++dy)
#pragma unroll
    for (int dx = 0; dx < 2; ++dx) {
      int px = (qy * 2 + dy) * 8 + qx * 2 + dx;
      const f32x4* mp = (const f32x4*)(Ml + px * 28);
#pragma unroll
      for (int v4 = 0; v4 < 7; ++v4) {
        f32x4 mv = mp[v4];
#pragma unroll
        for (int e = 0; e < 4; ++e) {
          int kk = v4 * 4 + e;
          if (kk < KK) m[dy * 2 + dx][kk] = mv[e];
        }
      }
    }
  __syncthreads();  // Pl ready

  // ---- carafe: 5 ch x 4 px per thread ----
  float pacc[5][4];
  const float* P0 = Pl + (g * 5) * 72 + qy * 9 + qx;
#pragma unroll
  for (int cc = 0; cc < 5; ++cc) {
    float p[KK];
#pragma unroll
    for (int i = 0; i < 5; ++i)
#pragma unroll
      for (int j = 0; j < 5; ++j) p[i * 5 + j] = P0[cc * 72 + i * 9 + j];
#pragma unroll
    for (int px = 0; px < 4; ++px) {
      float a = 0.f;
#pragma unroll
      for (int kk = 0; kk < KK; ++kk) a += p[kk] * m[px][kk];
      pacc[cc][px] = a;
    }
  }

  const int Yq = y0 + qy * 2, Xq = x0 + qx * 2;
#pragma unroll
  for (int cc = 0; cc < 5; ++cc) {
    float* ob = out + (((size_t)(b * CP + g * 5 + cc)) << 14);
#pragma unroll
    for (int dy = 0; dy < 2; ++dy) {
      f32x2 v2 = {pacc[cc][dy * 2 + 0], pacc[cc][dy * 2 + 1]};
      *(f32x2*)(ob + (Yq + dy) * WW + Xq) = v2;
    }
  }
}

extern "C" void kernel_launch(void* const* d_in, const int* in_sizes, int n_in,
                              void* d_out, int out_size, void* d_ws,
                              size_t ws_size, hipStream_t stream) {
  (void)in_sizes; (void)n_in; (void)out_size; (void)ws_size;
  const float* pred = (const float*)d_in[0];  // (4,80,64,64)
  const float* feat = (const float*)d_in[1];  // (4,256,128,128)
  const float* wc   = (const float*)d_in[2];  // (64,256)
  const float* bc   = (const float*)d_in[3];  // (64)
  const float* we   = (const float*)d_in[4];  // (25,64,3,3)
  const float* be   = (const float*)d_in[5];  // (25)
  float* out = (float*)d_out;                 // (4,80,128,128)

  char* ws = (char*)d_ws;
  short* guide = (short*)ws;             // 8,388,608 B (bf16, [b][y][x][c])
  short* web   = (short*)(ws + 8388608); // 36,864 B (bf16 [tap][kk32][c])

  hipLaunchKernelGGL(k_compress, dim3(1024), dim3(256), 0, stream,
                     feat, wc, bc, we, guide, web);
  hipLaunchKernelGGL(k_conv_carafe, dim3(1024), dim3(256), 0, stream,
                     guide, web, be, pred, out);
}